// Round 4
// baseline (2952.872 us; speedup 1.0000x reference)
//
#include <hip/hip_runtime.h>
#include <cstdint>
#include <cstddef>

typedef __bf16 bf16x8 __attribute__((ext_vector_type(8)));
typedef __bf16 bf16x4 __attribute__((ext_vector_type(4)));
typedef float  f32x4  __attribute__((ext_vector_type(4)));

// ---------------- ws layout (bytes) ----------------
#define WS_WFRAG   0           // 12,582,912 B : 64 slices * 48 kk * 4 nt * 64 lanes * 8 bf16
#define WS_XB      12582912    // 16,777,216 B : data bf16 [32][512][512]
#define WS_HBUF    29360128    //    131,072 B : h double buffer bf16 [2][32][1024]
#define WS_CNT     29491200    //        512 B : flags [2 groups][64 blocks]
#define WS_NEEDED  29491712

__device__ __forceinline__ float sigmoidf_(float x) {
    return 1.f / (1.f + __expf(-x));
}
__device__ __forceinline__ float tanhf_(float x) {
    x = fminf(fmaxf(x, -15.f), 15.f);
    float e2 = __expf(2.f * x);
    return (e2 - 1.f) / (e2 + 1.f);
}

// ---- prep: shuffle fused W = [Wx ; Wh] into bf16 B-fragment order ----
// 64 slices of 16 units. chunk index tid = ((s*48+kk)*4 + nt)*64 + l.
// col within slice: c = nt*16 + (l&15); uu = c>>2 (0..15), gi = c&3;
// global col n = gi*1024 + s*16 + uu. k0 = kk*32 + (l>>4)*8.
__global__ void __launch_bounds__(256) prep_w_kernel(const float* __restrict__ Wx,
                                                     const float* __restrict__ Wh,
                                                     __bf16* __restrict__ wfrag) {
    int tid = blockIdx.x * 256 + threadIdx.x;   // 0 .. 786431
    int l   = tid & 63;
    int m   = tid >> 6;
    int nt  = m & 3;
    int sk  = m >> 2;
    int kk  = sk % 48;
    int s   = sk / 48;
    int lc  = l & 15;
    int c   = nt * 16 + lc;
    int uu  = c >> 2;
    int gi  = c & 3;
    int n   = gi * 1024 + s * 16 + uu;
    int k0  = kk * 32 + (l >> 4) * 8;
    bf16x8 v;
#pragma unroll
    for (int j = 0; j < 8; ++j) {
        int k  = k0 + j;
        float f = (k < 512) ? Wx[k * 4096 + n] : Wh[(k - 512) * 4096 + n];
        v[j] = (__bf16)f;
    }
    ((bf16x8*)wfrag)[tid] = v;
}

// ---- prep: cast data fp32 -> bf16 ----
__global__ void __launch_bounds__(256) prep_x_kernel(const float* __restrict__ data,
                                                     __bf16* __restrict__ xb) {
    int tid = blockIdx.x * 256 + threadIdx.x;
    float4 v = ((const float4*)data)[tid];
    bf16x4 o;
    o[0] = (__bf16)v.x; o[1] = (__bf16)v.y; o[2] = (__bf16)v.z; o[3] = (__bf16)v.w;
    ((bf16x4*)xb)[tid] = o;
}

// ---- persistent LSTM kernel ----
// grid = 128 blocks x 256 threads (4 waves). block -> (g = bid>>6, s = bid&63).
// group g = batch rows [16g,16g+16); block owns 16 units [16s,16s+16).
// Wave w = N-tile w (16 gate cols). B-fragments RESIDENT IN REGISTERS (192 VGPR).
// x_t resident in registers (prefetched during previous poll). h staged once
// per block into LDS (shared by 4 waves). Barrier: per-block flag store +
// wave-parallel poll (64 lanes x 1 slot), no fences anywhere.
__global__ void __launch_bounds__(256, 1)
lstm_main(const __bf16* __restrict__ xb, const __bf16* __restrict__ wfrag,
          const float* __restrict__ bias, float* __restrict__ out,
          __bf16* __restrict__ hbuf, unsigned* __restrict__ cnt) {
    __shared__ __bf16 Hst[16384];    // h in A-frag order: 32 chunks * 64 lanes * 8
    __shared__ float  scr[1088];     // 4 waves * 272 (16x16 tile, stride 17)
    __shared__ __bf16 hpack[256];    // 16 rows * 16 units

    const int tid = threadIdx.x;
    const int l   = tid & 63;
    const int w   = tid >> 6;        // wave id == N-tile id (0..3)
    const int q   = l >> 4;
    const int r   = l & 15;
    const int bid = blockIdx.x;
    const int s   = bid & 63;
    const int g   = bid >> 6;
    const int gb0 = g * 16;

    // ---- B-fragments into registers (once, time-invariant) ----
    bf16x8 breg[48];
    {
        const __bf16* wsrc = wfrag + (size_t)s * 98304;
#pragma unroll
        for (int kk = 0; kk < 48; ++kk)
            breg[kk] = *(const bf16x8*)(wsrc + (kk * 4 + w) * 512 + l * 8);
    }

    const int uu = w * 4 + q;            // unit within block, 0..15
    const int u  = s * 16 + uu;          // global unit
    const float b_i = bias[u];
    const float b_f = bias[1024 + u];
    const float b_g = bias[2048 + u];
    const float b_o = bias[3072 + u];
    float cst = 0.f;

    unsigned* flags  = cnt + g * 64;     // one slot per block in this group
    unsigned* myflag = flags + s;

    // ---- prefetch x_0 into registers ----
    bf16x8 xreg[16];
    {
        const __bf16* xrow = xb + (size_t)(gb0 + r) * 512 * 512;
#pragma unroll
        for (int j = 0; j < 16; ++j)
            xreg[j] = *(const bf16x8*)(xrow + j * 32 + q * 8);
    }

    for (int t = 0; t < 512; ++t) {
        // ---- stage h_t into LDS (agent-scope atomic loads, block-cooperative) ----
        const __bf16* hsrc = hbuf + (size_t)((t & 1) * 32 + gb0) * 1024;
        unsigned long long hv[16];
#pragma unroll
        for (int j = 0; j < 8; ++j) {
            int e  = tid + 256 * j;          // entry 0..2047: chunk=e>>6, lane=e&63
            int m  = e >> 6;
            int le = e & 63;
            int rr = le & 15, qq = le >> 4;
            const unsigned long long* p =
                (const unsigned long long*)(hsrc + rr * 1024 + m * 32 + qq * 8);
            hv[2 * j]     = __hip_atomic_load(p,     __ATOMIC_RELAXED, __HIP_MEMORY_SCOPE_AGENT);
            hv[2 * j + 1] = __hip_atomic_load(p + 1, __ATOMIC_RELAXED, __HIP_MEMORY_SCOPE_AGENT);
        }

        // ---- x-part MFMAs: no LDS dependence, overlap the h round trip ----
        f32x4 a0 = {0,0,0,0}, a1 = {0,0,0,0}, a2 = {0,0,0,0}, a3 = {0,0,0,0};
#pragma unroll
        for (int j = 0; j < 16; j += 4) {
            a0 = __builtin_amdgcn_mfma_f32_16x16x32_bf16(xreg[j],     breg[j],     a0, 0, 0, 0);
            a1 = __builtin_amdgcn_mfma_f32_16x16x32_bf16(xreg[j + 1], breg[j + 1], a1, 0, 0, 0);
            a2 = __builtin_amdgcn_mfma_f32_16x16x32_bf16(xreg[j + 2], breg[j + 2], a2, 0, 0, 0);
            a3 = __builtin_amdgcn_mfma_f32_16x16x32_bf16(xreg[j + 3], breg[j + 3], a3, 0, 0, 0);
        }

        // ---- write staged h to LDS (waits on the atomic loads) ----
#pragma unroll
        for (int j = 0; j < 8; ++j) {
            int e = tid + 256 * j;
            ulonglong2 tmp;
            tmp.x = hv[2 * j];
            tmp.y = hv[2 * j + 1];
            *((ulonglong2*)(Hst + (size_t)e * 8)) = tmp;
        }
        __syncthreads();

        // ---- h-part MFMAs from LDS ----
#pragma unroll
        for (int m = 0; m < 32; m += 4) {
            bf16x8 h0 = *(const bf16x8*)(Hst + (m * 64 + l) * 8);
            bf16x8 h1 = *(const bf16x8*)(Hst + ((m + 1) * 64 + l) * 8);
            bf16x8 h2 = *(const bf16x8*)(Hst + ((m + 2) * 64 + l) * 8);
            bf16x8 h3 = *(const bf16x8*)(Hst + ((m + 3) * 64 + l) * 8);
            a0 = __builtin_amdgcn_mfma_f32_16x16x32_bf16(h0, breg[16 + m],     a0, 0, 0, 0);
            a1 = __builtin_amdgcn_mfma_f32_16x16x32_bf16(h1, breg[16 + m + 1], a1, 0, 0, 0);
            a2 = __builtin_amdgcn_mfma_f32_16x16x32_bf16(h2, breg[16 + m + 2], a2, 0, 0, 0);
            a3 = __builtin_amdgcn_mfma_f32_16x16x32_bf16(h3, breg[16 + m + 3], a3, 0, 0, 0);
        }
        f32x4 acc = (a0 + a1) + (a2 + a3);

        // ---- regroup gates (per-wave scratch, stride 17) ----
        float* sw = scr + w * 272;
#pragma unroll
        for (int rg = 0; rg < 4; ++rg) {
            sw[(l & 15) * 17 + q * 4 + rg] = acc[rg];   // col=l&15, row=q*4+rg
        }
        float xi = sw[(q * 4 + 0) * 17 + r];
        float xf = sw[(q * 4 + 1) * 17 + r];
        float xg = sw[(q * 4 + 2) * 17 + r];
        float xo = sw[(q * 4 + 3) * 17 + r];

        float ii = sigmoidf_(xi + b_i);
        float ff = sigmoidf_(xf + b_f);
        float gg = tanhf_(xg + b_g);
        float oo = sigmoidf_(xo + b_o);
        cst = ff * cst + ii * gg;
        float h = oo * tanhf_(cst);

        const int bglob = gb0 + r;

        if (t < 511) {
            hpack[r * 16 + uu] = (__bf16)h;
            __syncthreads();   // hpack complete
            if (tid < 64) {    // wave 0 publishes 16 rows x 32 B
                int row  = tid >> 2;
                int part = tid & 3;
                unsigned long long v = ((const unsigned long long*)hpack)[tid];
                unsigned long long* dst = (unsigned long long*)
                    (hbuf + (size_t)(((t + 1) & 1) * 32 + gb0 + row) * 1024 + s * 16) + part;
                __hip_atomic_store(dst, v, __ATOMIC_RELAXED, __HIP_MEMORY_SCOPE_AGENT);
            }
            __syncthreads();   // drains wave0's vmcnt -> h at coherent point
            if (tid == 0) {    // contention-free arrival: store own slot
                __hip_atomic_store(myflag, (unsigned)(t + 1),
                                   __ATOMIC_RELAXED, __HIP_MEMORY_SCOPE_AGENT);
            }
            // ---- off-critical-path: out store + x_{t+1} prefetch ----
            out[((size_t)bglob * 512 + t) * 1024 + u] = h;
            {
                const __bf16* xrow = xb + ((size_t)(gb0 + r) * 512 + (t + 1)) * 512;
#pragma unroll
                for (int j = 0; j < 16; ++j)
                    xreg[j] = *(const bf16x8*)(xrow + j * 32 + q * 8);
            }
            // ---- wave-parallel poll: lane i watches block i's flag ----
            if (w == 0) {
                const unsigned target = (unsigned)(t + 1);
                for (;;) {
                    unsigned v = __hip_atomic_load(flags + l, __ATOMIC_RELAXED,
                                                   __HIP_MEMORY_SCOPE_AGENT);
                    if (__all(v >= target)) break;
                }
            }
            __syncthreads();   // release (also drains out store + x prefetch)
        } else {
            out[((size_t)bglob * 512 + t) * 1024 + u] = h;
        }
    }
}

extern "C" void kernel_launch(void* const* d_in, const int* in_sizes, int n_in,
                              void* d_out, int out_size, void* d_ws, size_t ws_size,
                              hipStream_t stream) {
    const float* data = (const float*)d_in[0];
    const float* Wx   = (const float*)d_in[1];
    const float* Wh   = (const float*)d_in[2];
    const float* b    = (const float*)d_in[3];
    float* out = (float*)d_out;

    if (ws_size < (size_t)WS_NEEDED) return;

    char* ws = (char*)d_ws;
    __bf16*   wfrag = (__bf16*)(ws + WS_WFRAG);
    __bf16*   xbuf  = (__bf16*)(ws + WS_XB);
    __bf16*   hbuf  = (__bf16*)(ws + WS_HBUF);
    unsigned* cnt   = (unsigned*)(ws + WS_CNT);

    prep_w_kernel<<<3072, 256, 0, stream>>>(Wx, Wh, wfrag);
    prep_x_kernel<<<8192, 256, 0, stream>>>(data, xbuf);
    hipMemsetAsync(hbuf, 0, 131072 + 512, stream);   // h0 = 0, flags = 0
    lstm_main<<<128, 256, 0, stream>>>(xbuf, wfrag, b, out, hbuf, cnt);
}